// Round 1
// baseline (126.799 us; speedup 1.0000x reference)
//
#include <hip/hip_runtime.h>

// SNN forward: T=128, B=8192, I=2, H=256, O=2
//  cur[t,b,h] = x[t,b,0]*W1[h,0] + x[t,b,1]*W1[h,1]
//  scan over t:  reset = (mem > 1);  mem = 0.9*mem + cur - reset;  spk = (mem > 1)
//  out[b,o] = (mean of spk over t in [118,128)) dot W2[o,:]
//
// Numerics: must match numpy per-op fp32 rounding -> __fmul_rn/__fadd_rn/__fsub_rn
// (blocks FMA contraction), exact op order of the reference expressions.

#define T_STEPS 128
#define BATCH   8192
#define IN_N    2
#define HID     256
#define OUT_N   2
#define TAIL    10

__global__ __launch_bounds__(256) void snn_fwd(const float* __restrict__ x,
                                               const float* __restrict__ W1,
                                               const float* __restrict__ W2,
                                               float* __restrict__ out) {
    const int b = blockIdx.x;   // batch index, one block per b
    const int h = threadIdx.x;  // hidden unit, 0..255

    // per-thread weights
    const float w0 = W1[2 * h];
    const float w1 = W1[2 * h + 1];

    // x slice for this b: element (t,i) at xb[t*BATCH*IN_N + i] (block-uniform -> s_load)
    const float* xb = x + (size_t)b * IN_N;

    float mem   = 0.0f;
    float spike = 0.0f;  // spike of previous step == reset of current step
    float cnt   = 0.0f;

#pragma unroll 8
    for (int t = 0; t < T_STEPS - TAIL; ++t) {
        const float x0 = xb[(size_t)t * (BATCH * IN_N)];
        const float x1 = xb[(size_t)t * (BATCH * IN_N) + 1];
        // c = round(round(x0*w0) + round(x1*w1))   (numpy op order, no fma)
        const float c = __fadd_rn(__fmul_rn(x0, w0), __fmul_rn(x1, w1));
        // mem = ((0.9*mem) + c) - reset*1.0
        mem   = __fsub_rn(__fadd_rn(__fmul_rn(0.9f, mem), c), spike);
        spike = (mem > 1.0f) ? 1.0f : 0.0f;
    }
#pragma unroll
    for (int t = T_STEPS - TAIL; t < T_STEPS; ++t) {
        const float x0 = xb[(size_t)t * (BATCH * IN_N)];
        const float x1 = xb[(size_t)t * (BATCH * IN_N) + 1];
        const float c = __fadd_rn(__fmul_rn(x0, w0), __fmul_rn(x1, w1));
        mem   = __fsub_rn(__fadd_rn(__fmul_rn(0.9f, mem), c), spike);
        spike = (mem > 1.0f) ? 1.0f : 0.0f;
        cnt += spike;  // integer-valued, exact in fp32
    }

    // spk_avg = cnt / 10  (cnt in {0..10}, exact division result correctly rounded)
    const float avg = cnt / 10.0f;

    // partial products for the output GEMM: out[b,o] = sum_h avg*W2[o*HID+h]
    float p0 = avg * W2[h];
    float p1 = avg * W2[HID + h];

    // wave (64-lane) shuffle reduction
#pragma unroll
    for (int off = 32; off > 0; off >>= 1) {
        p0 += __shfl_down(p0, off, 64);
        p1 += __shfl_down(p1, off, 64);
    }

    __shared__ float s0[4], s1[4];
    const int wave = h >> 6;
    const int lane = h & 63;
    if (lane == 0) { s0[wave] = p0; s1[wave] = p1; }
    __syncthreads();
    if (h == 0) {
        out[(size_t)b * OUT_N + 0] = ((s0[0] + s0[1]) + (s0[2] + s0[3]));
        out[(size_t)b * OUT_N + 1] = ((s1[0] + s1[1]) + (s1[2] + s1[3]));
    }
}

extern "C" void kernel_launch(void* const* d_in, const int* in_sizes, int n_in,
                              void* d_out, int out_size, void* d_ws, size_t ws_size,
                              hipStream_t stream) {
    const float* x  = (const float*)d_in[0];  // (128, 8192, 2)
    const float* W1 = (const float*)d_in[1];  // (256, 2)
    const float* W2 = (const float*)d_in[2];  // (2, 256)
    float* out = (float*)d_out;               // (8192, 2)

    snn_fwd<<<BATCH, HID, 0, stream>>>(x, W1, W2, out);
}

// Round 2
// 109.078 us; speedup vs baseline: 1.1625x; 1.1625x over previous
//
#include <hip/hip_runtime.h>

// SNN forward: T=128, B=8192, I=2, H=256, O=2
//  cur[t,b,h] = x[t,b,0]*W1[h,0] + x[t,b,1]*W1[h,1]
//  scan: reset = (mem>1); mem = 0.9*mem + cur - reset; spk = (mem>1)
//  out[b,o] = (mean of spk over last 10 t) dot W2[o,:]
//
// R2: 8 batch rows per thread. Each block owns b0..b0+7 and stages its whole
// x tile (128 t x 8 b x 2 i = 8 KB) in LDS via coalesced float4 loads, so the
// scan reads wave-uniform LDS (broadcast, conflict-free) and every fetched HBM
// line is fully consumed (fixes the 8x over-fetch seen in R1). 8 independent
// recurrence chains per thread give the ILP to saturate VALU issue.
//
// Numerics: per-op fp32 rounding (__fmul_rn/__fadd_rn/__fsub_rn, no FMA),
// identical op order + identical reduction order/thread mapping to the R1
// kernel that measured absmax 0.0.

#define T_STEPS 128
#define BATCH   8192
#define IN_N    2
#define HID     256
#define OUT_N   2
#define TAIL    10
#define R       8

__global__ __launch_bounds__(256) void snn_fwd(const float* __restrict__ x,
                                               const float* __restrict__ W1,
                                               const float* __restrict__ W2,
                                               float* __restrict__ out) {
    const int h  = threadIdx.x;          // hidden unit 0..255
    const int b0 = blockIdx.x * R;       // first batch row of this block

    __shared__ float sx[T_STEPS * R * IN_N];   // 8 KB x tile
    __shared__ float red[4][R][OUT_N];         // cross-wave reduction buffer

    // ---- cooperative stage: x[t, b0:b0+8, 0:2] for all t (512 float4) ----
    {
        const float4* xg = (const float4*)x + (size_t)blockIdx.x * (R * IN_N / 4);
        float4* s4w = (float4*)sx;
        for (int j = h; j < T_STEPS * 4; j += 256) {
            const int t = j >> 2, k = j & 3;
            s4w[j] = xg[(size_t)t * (BATCH * IN_N / 4) + k];
        }
    }
    __syncthreads();

    const float w0 = W1[2 * h];
    const float w1 = W1[2 * h + 1];

    float mem[R], spk[R], cnt[R];
#pragma unroll
    for (int r = 0; r < R; ++r) { mem[r] = 0.0f; spk[r] = 0.0f; cnt[r] = 0.0f; }

    const float4* s4 = (const float4*)sx;

#define STEP(r, xa, xb)                                                          \
    {                                                                            \
        const float c = __fadd_rn(__fmul_rn((xa), w0), __fmul_rn((xb), w1));     \
        mem[r] = __fsub_rn(__fadd_rn(__fmul_rn(0.9f, mem[r]), c), spk[r]);       \
        spk[r] = (mem[r] > 1.0f) ? 1.0f : 0.0f;                                  \
    }

#pragma unroll 2
    for (int t = 0; t < T_STEPS - TAIL; ++t) {
        const float4 q0 = s4[t * 4 + 0];
        const float4 q1 = s4[t * 4 + 1];
        const float4 q2 = s4[t * 4 + 2];
        const float4 q3 = s4[t * 4 + 3];
        STEP(0, q0.x, q0.y) STEP(1, q0.z, q0.w)
        STEP(2, q1.x, q1.y) STEP(3, q1.z, q1.w)
        STEP(4, q2.x, q2.y) STEP(5, q2.z, q2.w)
        STEP(6, q3.x, q3.y) STEP(7, q3.z, q3.w)
    }
#pragma unroll 2
    for (int t = T_STEPS - TAIL; t < T_STEPS; ++t) {
        const float4 q0 = s4[t * 4 + 0];
        const float4 q1 = s4[t * 4 + 1];
        const float4 q2 = s4[t * 4 + 2];
        const float4 q3 = s4[t * 4 + 3];
        STEP(0, q0.x, q0.y) STEP(1, q0.z, q0.w)
        STEP(2, q1.x, q1.y) STEP(3, q1.z, q1.w)
        STEP(4, q2.x, q2.y) STEP(5, q2.z, q2.w)
        STEP(6, q3.x, q3.y) STEP(7, q3.z, q3.w)
#pragma unroll
        for (int r = 0; r < R; ++r) cnt[r] += spk[r];
    }
#undef STEP

    // ---- epilogue: out[b0+r, o] = (cnt[r]/10) dot W2[o,:] over h ----
    const float w2a = W2[h];
    const float w2b = W2[HID + h];
    float p0[R], p1[R];
#pragma unroll
    for (int r = 0; r < R; ++r) {
        const float avg = cnt[r] / 10.0f;
        p0[r] = avg * w2a;
        p1[r] = avg * w2b;
    }

    // wave (64-lane) shuffle reduction — same order as the R1-passing kernel
#pragma unroll
    for (int off = 32; off > 0; off >>= 1) {
#pragma unroll
        for (int r = 0; r < R; ++r) {
            p0[r] += __shfl_down(p0[r], off, 64);
            p1[r] += __shfl_down(p1[r], off, 64);
        }
    }

    const int wave = h >> 6;
    const int lane = h & 63;
    if (lane == 0) {
#pragma unroll
        for (int r = 0; r < R; ++r) { red[wave][r][0] = p0[r]; red[wave][r][1] = p1[r]; }
    }
    __syncthreads();
    if (h < R * OUT_N) {
        const int r = h >> 1, o = h & 1;
        out[(size_t)(b0 + r) * OUT_N + o] =
            (red[0][r][o] + red[1][r][o]) + (red[2][r][o] + red[3][r][o]);
    }
}

extern "C" void kernel_launch(void* const* d_in, const int* in_sizes, int n_in,
                              void* d_out, int out_size, void* d_ws, size_t ws_size,
                              hipStream_t stream) {
    const float* x  = (const float*)d_in[0];  // (128, 8192, 2)
    const float* W1 = (const float*)d_in[1];  // (256, 2)
    const float* W2 = (const float*)d_in[2];  // (2, 256)
    float* out = (float*)d_out;               // (8192, 2)

    snn_fwd<<<BATCH / R, HID, 0, stream>>>(x, W1, W2, out);
}